// Round 14
// baseline (2237.752 us; speedup 1.0000x reference)
//
#include <hip/hip_runtime.h>
#include <stdint.h>
#include <math.h>

typedef unsigned long long u64;
typedef unsigned int u32;
typedef unsigned char u8;
typedef short s16x8 __attribute__((ext_vector_type(8)));
typedef float f32x4 __attribute__((ext_vector_type(4)));

#define ATOT 242991    // total anchors per batch
#define PXTOT 80997    // total pixels per batch
#define PXPAD 82971    // padded (H+2)x(W+2) pixels per batch

__device__ __constant__ int    d_Hs[5]      = {200,100,50,25,13};
__device__ __constant__ int    d_Ws[5]      = {304,152,76,38,19};
__device__ __constant__ int    d_Wp[5]      = {306,154,78,40,21};
__device__ __constant__ int    d_stridec[5] = {4,8,16,32,64};
__device__ __constant__ double d_sized[5]   = {32.0,64.0,128.0,256.0,512.0};
__device__ __constant__ int    d_off[5]     = {0,182400,228000,239400,242250};
__device__ __constant__ int    d_pxoff[6]   = {0,60800,76000,79800,80750,80997};
__device__ __constant__ int    d_poff[5]    = {0,61812,77520,81576,82656};
__device__ __constant__ int    d_Ncand[5]   = {182400,45600,11400,2850,741};
// xcvt: 32-px chunks per level {1900,475,119,30,8} -> 2532/batch
__device__ __constant__ int    d_xcb[5]     = {0,1900,2375,2494,2524};
// conv: single-row 64-px tiles: {1000,300,100,25,13} = 1438/batch
__device__ __constant__ int    d_ctb[5]     = {0,1000,1300,1400,1425};
__device__ __constant__ int    d_tX[5]      = {5,3,2,1,1};
// border pixels per level: 2*(W+2)+2*H -> cumsum
__device__ __constant__ int    d_bcum[6]    = {0,1012,1520,1776,1906,1974};

__device__ __forceinline__ u32 f2k32(float f) {
  u32 u = __float_as_uint(f);
  return (u & 0x80000000u) ? ~u : (u | 0x80000000u);
}
__device__ __forceinline__ float k2f32(u32 k) {
  u32 u = (k & 0x80000000u) ? (k & 0x7FFFFFFFu) : ~k;
  return __uint_as_float(u);
}
__device__ __forceinline__ u64 d2k(double d) {
  u64 b = (u64)__double_as_longlong(d);
  return (b & 0x8000000000000000ull) ? ~b : (b | 0x8000000000000000ull);
}
__device__ __forceinline__ unsigned short f2bf(float v) {   // RNE (weights)
  u32 b = __float_as_uint(v);
  return (unsigned short)((b + 0x7FFFu + ((b >> 16) & 1u)) >> 16);
}

// ---------------- merged prep: wtrans (2304 blks) + wcvt (288) + border_zero (124) ----
__global__ void prep_k(const float* __restrict__ w, float* __restrict__ wt,
                       short* __restrict__ wbh, short* __restrict__ xh,
                       short* __restrict__ xl) {
  int blk = blockIdx.x;
  int t = threadIdx.x;
  if (blk < 2304) {
    // wtrans: w[oc][ic][3][3] -> wt[ic][tap][oc]  (fp32, r9-proven rescore operand)
    int gid = blk * 256 + t;
    int oc = gid & 255;
    int rest = gid >> 8;
    int ic = rest / 9, tap = rest % 9;
    wt[gid] = w[(oc * 256 + ic) * 9 + tap];
  } else if (blk < 2304 + 288) {
    int gid = (blk - 2304) * 256 + t;
    if (gid >= 73728) return;
    int lane = gid & 63;
    int rest = gid >> 6;
    int oct = rest & 15, rs = rest >> 4;
    int slice = rs & 7, tap = rs >> 3;
    int oc = oct * 16 + (lane & 15);
    int icb = slice * 32 + (lane >> 4) * 8;
    size_t ob = (size_t)gid * 8;
#pragma unroll
    for (int j = 0; j < 8; ++j)
      wbh[ob + j] = (short)f2bf(w[(oc * 256 + icb + j) * 9 + tap]);
  } else {
    int tid = (blk - 2592) * 256 + t;
    if (tid >= 2 * 1974 * 8) return;
    int oct = tid & 7;
    int rest = tid >> 3;
    int b = rest / 1974;
    int bi = rest % 1974;
    int lvl = 0;
#pragma unroll
    for (int l = 1; l < 5; ++l) if (bi >= d_bcum[l]) lvl = l;
    int li = bi - d_bcum[lvl];
    int W = d_Ws[lvl], H = d_Hs[lvl], Wp = d_Wp[lvl];
    int py, px;
    if (li < Wp)            { py = 0;     px = li; }
    else if (li < 2 * Wp)   { py = H + 1; px = li - Wp; }
    else { int rem = li - 2 * Wp; py = 1 + rem / 2; px = (rem & 1) ? (W + 1) : 0; }
    size_t base = ((size_t)(b * PXPAD + d_poff[lvl]) + (size_t)py * Wp + px) * 256
                + (size_t)oct * 32;
    s16x8 z = (s16x8){0,0,0,0,0,0,0,0};
#pragma unroll
    for (int j = 0; j < 4; ++j) {
      *(s16x8*)(xh + base + j * 8) = z;
      *(s16x8*)(xl + base + j * 8) = z;
    }
  }
}

// ---------------- x NCHW fp32 -> NHWC-padded BITWISE split (hi=top16, lo=bottom16) ----
__global__ __launch_bounds__(256) void xcvt_k(
    const float* __restrict__ x0, const float* __restrict__ x1,
    const float* __restrict__ x2, const float* __restrict__ x3,
    const float* __restrict__ x4, short* __restrict__ xh, short* __restrict__ xl)
{
  __shared__ float tile[32 * 257];
  const int bid = blockIdx.x;
  const int b = bid / 2532;
  int r = bid % 2532;
  int lvl = 0;
#pragma unroll
  for (int l2 = 1; l2 < 5; ++l2) if (r >= d_xcb[l2]) lvl = l2;
  const int chunk = r - d_xcb[lvl];
  const int H = d_Hs[lvl], W = d_Ws[lvl], HW = H * W, Wp = d_Wp[lvl];
  const int px0 = chunk * 32;
  const float* xs[5] = {x0, x1, x2, x3, x4};
  const float* xb = xs[lvl] + (size_t)b * 256 * HW;
  const int t = threadIdx.x;

  for (int icg = 0; icg < 32; ++icg) {
    int ic = icg * 8 + (t >> 5);
    int px = px0 + (t & 31);
    float v = (px < HW) ? xb[(size_t)ic * HW + px] : 0.f;
    tile[(t & 31) * 257 + ic] = v;
  }
  __syncthreads();
  int px = t >> 3, sub = t & 7;
  int gpx = px0 + px;
  if (gpx < HW) {
    int yy = gpx / W, xx = gpx % W;
    size_t pxbase = ((size_t)(b * PXPAD + d_poff[lvl]) +
                     (size_t)(yy + 1) * Wp + (xx + 1)) * 256;
#pragma unroll
    for (int q = 0; q < 4; ++q) {
      int ch0 = q * 64 + sub * 8;
      s16x8 hi, lo;
#pragma unroll
      for (int j = 0; j < 8; ++j) {
        u32 bits = __float_as_uint(tile[px * 257 + ch0 + j]);
        hi[j] = (short)(bits >> 16);       // truncated bf16 (screen operand)
        lo[j] = (short)(bits & 0xFFFFu);   // exact low bits (rescore reconstruct)
      }
      *(s16x8*)(xh + pxbase + ch0) = hi;
      *(s16x8*)(xl + pxbase + ch0) = lo;
    }
  }
}

// ---------------- 1-term bf16 MFMA conv3x3 + ReLU + in-register cls screen ----------
// 8 waves x 32 oc/wave (acc halved to 32 regs -> 4-5 waves/SIMD occupancy lever).
__global__ __launch_bounds__(512) void conv_mfma_k(
    const short* __restrict__ xh, const short* __restrict__ wbh,
    const float* __restrict__ convb, const float* __restrict__ clsw,
    const float* __restrict__ clsb, float* __restrict__ scr32)
{
  __shared__ float zl[8][64][3];
  const int bid = blockIdx.x;
  const int b = bid / 1438;
  int r = bid % 1438;
  int lvl = 0;
#pragma unroll
  for (int l2 = 1; l2 < 5; ++l2) if (r >= d_ctb[l2]) lvl = l2;
  const int lid = r - d_ctb[lvl];
  const int tX = d_tX[lvl];
  const int y = lid / tX, x0 = (lid % tX) * 64;
  const int W = d_Ws[lvl], Wp = d_Wp[lvl];
  const size_t pbase = (size_t)(b * PXPAD + d_poff[lvl]);

  const int t = threadIdx.x;
  const int lane = t & 63;
  const int wid = t >> 6;                 // 0..7
  const int aoff = (lane & 15) * 256 + (lane >> 4) * 8;

  f32x4 acc[4][2];
#pragma unroll
  for (int m = 0; m < 4; ++m)
#pragma unroll
    for (int o = 0; o < 2; ++o) acc[m][o] = (f32x4){0.f, 0.f, 0.f, 0.f};

#pragma unroll 1
  for (int tap = 0; tap < 9; ++tap) {
    const int ky = tap / 3, kx = tap % 3;
    const size_t re = (pbase + (size_t)(y + ky) * Wp + (x0 + kx)) * 256;
    const short* pa = xh + re;
    const short* pbh = wbh + (size_t)tap * 8 * 16 * 512;
#pragma unroll 1
    for (int slice = 0; slice < 8; ++slice) {
      s16x8 bh[2], a[4];
#pragma unroll
      for (int o = 0; o < 2; ++o) {
        size_t bo = ((size_t)(slice * 16 + wid * 2 + o) * 64 + lane) * 8;
        bh[o] = *(const s16x8*)(pbh + bo);
      }
#pragma unroll
      for (int m = 0; m < 4; ++m) {
        size_t ao = (size_t)aoff + slice * 32 + m * 4096;
        a[m] = *(const s16x8*)(pa + ao);
      }
#pragma unroll
      for (int m = 0; m < 4; ++m)
#pragma unroll
        for (int o = 0; o < 2; ++o)
          acc[m][o] = __builtin_amdgcn_mfma_f32_16x16x32_bf16(a[m], bh[o], acc[m][o], 0, 0, 0);
    }
  }

  float bb[2], cw0[2], cw1[2], cw2[2];
#pragma unroll
  for (int o = 0; o < 2; ++o) {
    int oc = wid * 32 + o * 16 + (lane & 15);
    bb[o]  = convb[oc];
    cw0[o] = clsw[0 * 256 + oc];
    cw1[o] = clsw[1 * 256 + oc];
    cw2[o] = clsw[2 * 256 + oc];
  }
#pragma unroll
  for (int m = 0; m < 4; ++m) {
#pragma unroll
    for (int q = 0; q < 4; ++q) {
      float h0 = fmaxf(acc[m][0][q] + bb[0], 0.f);
      float h1 = fmaxf(acc[m][1][q] + bb[1], 0.f);
      float z0 = fmaf(h0, cw0[0], h1 * cw0[1]);
      float z1 = fmaf(h0, cw1[0], h1 * cw1[1]);
      float z2 = fmaf(h0, cw2[0], h1 * cw2[1]);
      z0 += __shfl_xor(z0, 1); z0 += __shfl_xor(z0, 2); z0 += __shfl_xor(z0, 4); z0 += __shfl_xor(z0, 8);
      z1 += __shfl_xor(z1, 1); z1 += __shfl_xor(z1, 2); z1 += __shfl_xor(z1, 4); z1 += __shfl_xor(z1, 8);
      z2 += __shfl_xor(z2, 1); z2 += __shfl_xor(z2, 2); z2 += __shfl_xor(z2, 4); z2 += __shfl_xor(z2, 8);
      if ((lane & 15) == 0) {
        int slot = m * 16 + (lane >> 4) * 4 + q;
        zl[wid][slot][0] = z0; zl[wid][slot][1] = z1; zl[wid][slot][2] = z2;
      }
    }
  }
  __syncthreads();
  if (t < 192) {
    int slot = t / 3, head = t % 3;
    int col = x0 + slot;
    if (col < W) {
      float z = clsb[head];
#pragma unroll
      for (int wv = 0; wv < 8; ++wv) z += zl[wv][slot][head];
      int pix = y * W + col;
      scr32[(size_t)b * ATOT + d_off[lvl] + (size_t)pix * 3 + head] =
          1.f / (1.f + expf(-z));
    }
  }
}

// ---------------- PHASE B: fp32 radix select with safety margin ----------------
__device__ __forceinline__ void locate(int gid, int& b, int& r, int& lvl) {
  b = gid / ATOT; r = gid % ATOT;
  lvl = (r < 182400) ? 0 : (r < 228000) ? 1 : (r < 239400) ? 2 : (r < 242250) ? 3 : 4;
}

__global__ void hist_hi_k(const float* __restrict__ scr, u32* __restrict__ hist) {
  int gid = blockIdx.x * 256 + threadIdx.x;
  if (gid >= 2 * ATOT) return;
  int b, r, lvl; locate(gid, b, r, lvl);
  u32 key = f2k32(scr[gid]);
  int rep = blockIdx.x & 3;
  atomicAdd(&hist[((((b * 5 + lvl) << 2) | rep) << 16) + (key >> 16)], 1u);
}

__global__ void scan_hi_k(const u32* __restrict__ hist, int* __restrict__ meta) {
  int bl = blockIdx.x, lvl = bl % 5;
  u32 k_sel = (u32)min(1000, d_Ncand[lvl]);
  const u32* h = hist + ((size_t)bl << 18);
  __shared__ u32 part[256];
  __shared__ u32 row[256];
  __shared__ int csel;
  __shared__ u32 cumsh;
  int t = threadIdx.x;
  u32 s = 0;
  for (int v = 0; v < 256; ++v) {
    int idx = t * 256 + v;
    s += h[idx] + h[65536 + idx] + h[131072 + idx] + h[196608 + idx];
  }
  part[t] = s;
  __syncthreads();
  if (t == 0) {
    u32 cum = 0; int c = 255;
    for (; c > 0; --c) { if (cum + part[c] >= k_sel) break; cum += part[c]; }
    csel = c; cumsh = cum;
  }
  __syncthreads();
  {
    int idx = csel * 256 + t;
    row[t] = h[idx] + h[65536 + idx] + h[131072 + idx] + h[196608 + idx];
  }
  __syncthreads();
  if (t == 0) {
    u32 cum = cumsh;
    int pivot = csel * 256;
    for (int v = 255; v >= 0; --v) {
      if (cum + row[v] >= k_sel) { pivot = csel * 256 + v; break; }
      cum += row[v];
    }
    meta[bl * 8 + 0] = pivot;
    meta[bl * 8 + 1] = (int)cum;
  }
}

__global__ void hist_lo_k(const float* __restrict__ scr, const int* __restrict__ meta,
                          u32* __restrict__ hist) {
  int gid = blockIdx.x * 256 + threadIdx.x;
  if (gid >= 2 * ATOT) return;
  int b, r, lvl; locate(gid, b, r, lvl);
  int bl = b * 5 + lvl;
  u32 key = f2k32(scr[gid]);
  if ((int)(key >> 16) == meta[bl * 8 + 0]) {
    int rep = blockIdx.x & 3;
    atomicAdd(&hist[(((bl << 2) | rep) << 16) + (key & 0xFFFFu)], 1u);
  }
}

__global__ void scan_lo_k(const u32* __restrict__ hist, int* __restrict__ meta) {
  int bl = blockIdx.x, lvl = bl % 5;
  u32 k_sel = (u32)min(1000, d_Ncand[lvl]);
  const u32* h = hist + ((size_t)bl << 18);
  __shared__ u32 part[256];
  __shared__ u32 row[256];
  __shared__ int csel;
  __shared__ u32 cumsh;
  int t = threadIdx.x;
  u32 s = 0;
  for (int v = 0; v < 256; ++v) {
    int idx = t * 256 + v;
    s += h[idx] + h[65536 + idx] + h[131072 + idx] + h[196608 + idx];
  }
  part[t] = s;
  __syncthreads();
  if (t == 0) {
    u32 cum = (u32)meta[bl * 8 + 1];
    int c = 255;
    for (; c > 0; --c) { if (cum + part[c] >= k_sel) break; cum += part[c]; }
    csel = c; cumsh = cum;
  }
  __syncthreads();
  {
    int idx = csel * 256 + t;
    row[t] = h[idx] + h[65536 + idx] + h[131072 + idx] + h[196608 + idx];
  }
  __syncthreads();
  if (t == 0) {
    u32 cum = cumsh;
    int pivot = csel * 256;
    for (int v = 255; v >= 0; --v) {
      if (cum + row[v] >= k_sel) { pivot = csel * 256 + v; break; }
      cum += row[v];
    }
    u32 P = (((u32)meta[bl * 8 + 0]) << 16) | (u32)pivot;   // exact fp32 kth key
    u32 T = f2k32(k2f32(P) - 5e-3f);                        // margin covers 1-term err
    if (d_Ncand[lvl] <= 1000) T = 0;                        // keep all
    meta[bl * 8 + 2] = (int)T;
    meta[bl * 8 + 4] = 0;   // compact counter
  }
}

__global__ void compact_k(const float* __restrict__ scr, int* __restrict__ meta,
                          u32* __restrict__ complist, u8* __restrict__ flags) {
  int gid = blockIdx.x * 256 + threadIdx.x;
  if (gid >= 2 * ATOT) return;
  int b, r, lvl; locate(gid, b, r, lvl);
  int bl = b * 5 + lvl;
  u32 key = f2k32(scr[gid]);
  if (key >= (u32)meta[bl * 8 + 2]) {
    int pos = atomicAdd(&meta[bl * 8 + 4], 1);
    if (pos < 8192) {
      u32 li = (u32)(r - d_off[lvl]);
      complist[bl * 8192 + pos] = li;
      flags[b * PXTOT + d_pxoff[lvl] + li / 3] = 1;
    }
  }
}

__global__ void pxcompact_k(u8* __restrict__ flags, u32* __restrict__ worklist,
                            int* __restrict__ wlcount) {
  int gid = blockIdx.x * 256 + threadIdx.x;
  if (gid >= 2 * PXTOT) return;
  if (flags[gid]) {
    flags[gid] = 0;
    int pos = atomicAdd(wlcount, 1);
    if (pos < 65536) worklist[pos] = (u32)gid;
  }
}

// ---------------- PHASE C: sparse fp64 rescore (round-9 proven structure) -----------
// x reconstructed BIT-EXACTLY as (xh<<16)|xl; fp32 wt (2.36 MB, L2-resident).
#define RSG 2048
__global__ __launch_bounds__(256) void rescore_k(
    const short* __restrict__ xh, const short* __restrict__ xl,
    const float* __restrict__ wt, const float* __restrict__ convb,
    const float* __restrict__ clsw, const float* __restrict__ clsb,
    const float* __restrict__ regw, const float* __restrict__ regb,
    const u32* __restrict__ worklist, const int* __restrict__ wlcount,
    double* __restrict__ scr64, double* __restrict__ reg64)
{
  __shared__ float xlb[4 * 2304];   // [slot][ic*9+tap]  36.9 KB
  __shared__ double hl[4 * 256];    // 8 KB -> total 45,056 B (r9-proven)
  const int t = threadIdx.x;
  int count = *wlcount; if (count > 65536) count = 65536;

  for (int base = blockIdx.x * 4; base < count; base += RSG * 4) {
    int sb[4], slvl[4], spix[4];
    size_t pb0[4];
    bool valid[4];
#pragma unroll
    for (int s = 0; s < 4; ++s) {
      int w = base + s;
      valid[s] = (w < count);
      sb[s] = 0; slvl[s] = 0; spix[s] = 0; pb0[s] = 0;
      if (valid[s]) {
        u32 g = worklist[w];
        int b = (int)(g / PXTOT), lp = (int)(g % PXTOT);
        int lvl = 0;
#pragma unroll
        for (int l = 1; l < 5; ++l) if (lp >= d_pxoff[l]) lvl = l;
        int pix = lp - d_pxoff[lvl];
        int W = d_Ws[lvl], Wp = d_Wp[lvl];
        int py = pix / W, px = pix % W;
        sb[s] = b; slvl[s] = lvl; spix[s] = pix;
        pb0[s] = ((size_t)(b * PXPAD + d_poff[lvl]) + (size_t)py * Wp + px) * 256;
      }
    }
    __syncthreads();
#pragma unroll
    for (int s = 0; s < 4; ++s) {
      if (valid[s]) {
        int Wp = d_Wp[slvl[s]];
        for (int i = t; i < 1152; i += 256) {
          int tap = i >> 7, pair = i & 127;
          int ky = tap / 3, kx = tap % 3;
          size_t po = pb0[s] + ((size_t)ky * Wp + kx) * 256 + (size_t)pair * 2;
          u32 vh = *(const u32*)(xh + po);
          u32 vl = *(const u32*)(xl + po);
          float xa  = __uint_as_float(((vh & 0xFFFFu) << 16) | (vl & 0xFFFFu));
          float xb2 = __uint_as_float((vh & 0xFFFF0000u) | (vl >> 16));
          xlb[s * 2304 + (pair * 2) * 9 + tap] = xa;
          xlb[s * 2304 + (pair * 2 + 1) * 9 + tap] = xb2;
        }
      }
    }
    __syncthreads();
    double h[4] = {0.0, 0.0, 0.0, 0.0};
    for (int ic = 0; ic < 256; ++ic) {
      double wd[9];
#pragma unroll
      for (int tap = 0; tap < 9; ++tap)
        wd[tap] = (double)wt[(ic * 9 + tap) * 256 + t];
#pragma unroll
      for (int s = 0; s < 4; ++s) {
        const float* xp = &xlb[s * 2304 + ic * 9];
#pragma unroll
        for (int tap = 0; tap < 9; ++tap)
          h[s] = fma((double)xp[tap], wd[tap], h[s]);
      }
    }
    double bias = (double)convb[t];
#pragma unroll
    for (int s = 0; s < 4; ++s) {
      h[s] = fmax(h[s] + bias, 0.0);
      hl[s * 256 + t] = h[s];
    }
    __syncthreads();
    {
      int s = t >> 6, lane = t & 63;
      if (valid[s]) {
        int lvl = slvl[s];
        size_t g3 = (size_t)sb[s] * ATOT + d_off[lvl] + (size_t)spix[s] * 3;
        for (int head = 0; head < 15; ++head) {
          const float* hw = (head < 3) ? (clsw + head * 256) : (regw + (head - 3) * 256);
          double part = 0.0;
#pragma unroll
          for (int q = 0; q < 4; ++q) {
            int oc = lane + q * 64;
            part = fma(hl[s * 256 + oc], (double)hw[oc], part);
          }
          part += __shfl_xor(part, 32);
          part += __shfl_xor(part, 16);
          part += __shfl_xor(part, 8);
          part += __shfl_xor(part, 4);
          part += __shfl_xor(part, 2);
          part += __shfl_xor(part, 1);
          if (lane == 0) {
            double z = part + (double)((head < 3) ? clsb[head] : regb[head - 3]);
            if (head < 3) scr64[g3 + head] = 1.0 / (1.0 + exp(-z));
            else { int hh = head - 3; reg64[(g3 + (hh >> 2)) * 4 + (hh & 3)] = z; }
          }
        }
      }
    }
    __syncthreads();
  }
}

// ---------------- PHASE D: keys built inline, sort, decode, NMS, final --------------
__device__ void bitonic_desc_n(u64* s, int SZ) {
  int t = threadIdx.x;
  for (int k = 2; k <= SZ; k <<= 1) {
    for (int j = k >> 1; j > 0; j >>= 1) {
      __syncthreads();
      for (int i = t; i < (SZ >> 1); i += 1024) {
        int l = (i << 1) - (i & (j - 1));
        int m = l + j;
        bool up = ((l & k) == 0);
        u64 a = s[l], bb = s[m];
        if ((a < bb) == up) { s[l] = bb; s[m] = a; }
      }
    }
  }
  __syncthreads();
}

__global__ __launch_bounds__(1024) void sort_level_k(const u32* __restrict__ complist,
                                                     const int* __restrict__ meta,
                                                     const double* __restrict__ scr64,
                                                     int* __restrict__ topidx) {
  int bl = blockIdx.x, lvl = bl % 5;
  int b = bl / 5;
  int k_sel = min(1000, d_Ncand[lvl]);
  __shared__ u64 s[8192];
  int M = meta[bl * 8 + 4]; if (M > 8192) M = 8192;
  int SZ = (M <= 2048) ? 2048 : 8192;
  for (int i = threadIdx.x; i < SZ; i += 1024) {
    u64 key = 0;
    if (i < M) {
      u32 li = complist[bl * 8192 + i];
      double sc = scr64[(size_t)b * ATOT + d_off[lvl] + li];
      key = ((d2k(sc) >> 18) << 18) | (u64)(0x3FFFFu - li);
    }
    s[i] = key;
  }
  __syncthreads();
  bitonic_desc_n(s, SZ);
  for (int r = threadIdx.x; r < 1000; r += 1024) {
    int v = -1;
    if (r < k_sel && r < M) v = (int)(0x3FFFFu - (u32)(s[r] & 0x3FFFFu));
    topidx[bl * 1000 + r] = v;
  }
}

__global__ void decode_k(const int* __restrict__ topidx, const double* __restrict__ scr64,
                         const double* __restrict__ reg64, double* __restrict__ boxes,
                         double* __restrict__ sc0) {
  int gid = blockIdx.x * 256 + threadIdx.x;
  if (gid >= 10000) return;
  int bl = gid / 1000, rank = gid % 1000;
  int b = bl / 5, lvl = bl % 5;
  int idx = topidx[bl * 1000 + rank];
  double X1 = 0.0, Y1 = 0.0, X2 = 0.0, Y2 = 0.0, sc = -1.0;
  if (idx >= 0) {
    size_t g = (size_t)b * ATOT + d_off[lvl] + idx;
    double s = scr64[g];
    double dx = reg64[g * 4 + 0], dy = reg64[g * 4 + 1];
    const double BCLIP = 4.135166556742356;
    double dw = fmin(reg64[g * 4 + 2], BCLIP);
    double dh = fmin(reg64[g * 4 + 3], BCLIP);
    int a = idx % 3, pix = idx / 3;
    int W = d_Ws[lvl];
    int py = pix / W, px = pix % W;
    double r = (a == 0) ? 2.0 : (a == 1) ? 1.0 : 0.5;
    double hr = sqrt(r);
    double size = d_sized[lvl];
    double wsz = size / hr, hsz = size * hr;
    double bx2 = rint(wsz * 0.5), by2 = rint(hsz * 0.5);
    double bx1 = rint(-(wsz * 0.5)), by1 = rint(-(hsz * 0.5));
    double sx = (double)(px * d_stridec[lvl]), sy = (double)(py * d_stridec[lvl]);
    double x1 = sx + bx1, yy1 = sy + by1;
    double x2 = sx + bx2, yy2 = sy + by2;
    double pw = x2 - x1, ph = yy2 - yy1;
    double pcx = x1 + 0.5 * pw, pcy = yy1 + 0.5 * ph;
    double cx = dx * pw + pcx, cy = dy * ph + pcy;
    double w = exp(dw) * pw, h = exp(dh) * ph;
    X1 = fmin(fmax(cx - 0.5 * w, 0.0), 1216.0);
    Y1 = fmin(fmax(cy - 0.5 * h, 0.0), 800.0);
    X2 = fmin(fmax(cx + 0.5 * w, 0.0), 1216.0);
    Y2 = fmin(fmax(cy + 0.5 * h, 0.0), 800.0);
    sc = ((X2 - X1) > 0.001 && (Y2 - Y1) > 0.001) ? s : -1.0;
  }
  double* bp = boxes + (size_t)(bl * 1000 + rank) * 4;
  bp[0] = X1; bp[1] = Y1; bp[2] = X2; bp[3] = Y2;
  sc0[bl * 1000 + rank] = sc;
}

__global__ __launch_bounds__(256) void nms_mask_k(const double* __restrict__ boxes,
                                                  u64* __restrict__ gmask) {
  int blk = blockIdx.x;
  int bl = blk >> 2, qt = blk & 3;
  __shared__ double X1[1000], Y1[1000], X2[1000], Y2[1000], AR[1000];
  int t = threadIdx.x;
  for (int i = t; i < 1000; i += 256) {
    const double* bp = boxes + (size_t)(bl * 1000 + i) * 4;
    double x1 = bp[0], y1 = bp[1], x2 = bp[2], y2 = bp[3];
    X1[i] = x1; Y1[i] = y1; X2[i] = x2; Y2[i] = y2;
    AR[i] = (x2 - x1) * (y2 - y1);
  }
  __syncthreads();
  if (t < 250) {
    int i = qt * 250 + t;
    double ax1 = X1[i], ay1 = Y1[i], ax2 = X2[i], ay2 = Y2[i], aa = AR[i];
    u64* gm = gmask + (size_t)bl * 16000 + (size_t)i * 16;
    for (int wj = 0; wj < 16; ++wj) {
      u64 bits = 0;
      int jb0 = wj * 64;
      for (int jb = 0; jb < 64; ++jb) {
        int j = jb0 + jb;
        if (j <= i || j >= 1000) continue;
        double lx = fmax(ax1, X1[j]), ly = fmax(ay1, Y1[j]);
        double rx = fmin(ax2, X2[j]), ry = fmin(ay2, Y2[j]);
        double ww = fmax(rx - lx, 0.0), hh = fmax(ry - ly, 0.0);
        double inter = ww * hh;
        double uni = (aa + AR[j]) - inter;
        double iou = inter / fmax(uni, 1e-9);
        if (iou > 0.7) bits |= (1ull << jb);
      }
      gm[wj] = bits;
    }
  }
}

__global__ void nms_scan_k(double* __restrict__ sc0, const u64* __restrict__ gmask) {
  int bl = blockIdx.x;
  int lane = threadIdx.x;
  const u64* gm = gmask + (size_t)bl * 16000;
  u64 keepw = 0;
  if (lane < 16) {
    for (int jb = 0; jb < 64; ++jb) {
      int j = lane * 64 + jb;
      if (j < 1000 && sc0[bl * 1000 + j] > -0.5) keepw |= (1ull << jb);
    }
  }
  u64 m0 = 0, m1 = 0, m2 = 0, m3 = 0;
  if (lane < 16) {
    m0 = gm[0 * 16 + lane]; m1 = gm[1 * 16 + lane];
    m2 = gm[2 * 16 + lane]; m3 = gm[3 * 16 + lane];
  }
  for (int i = 0; i < 1000; i += 4) {
    u64 n0 = 0, n1 = 0, n2 = 0, n3 = 0;
    if (lane < 16 && i + 4 < 1000) {
      n0 = gm[(i + 4) * 16 + lane]; n1 = gm[(i + 5) * 16 + lane];
      n2 = gm[(i + 6) * 16 + lane]; n3 = gm[(i + 7) * 16 + lane];
    }
    { u64 kw = __shfl(keepw, (i    ) >> 6); if ((kw >> ((i    ) & 63)) & 1) { if (lane < 16) keepw &= ~m0; } }
    { u64 kw = __shfl(keepw, (i + 1) >> 6); if ((kw >> ((i + 1) & 63)) & 1) { if (lane < 16) keepw &= ~m1; } }
    { u64 kw = __shfl(keepw, (i + 2) >> 6); if ((kw >> ((i + 2) & 63)) & 1) { if (lane < 16) keepw &= ~m2; } }
    { u64 kw = __shfl(keepw, (i + 3) >> 6); if ((kw >> ((i + 3) & 63)) & 1) { if (lane < 16) keepw &= ~m3; } }
    m0 = n0; m1 = n1; m2 = n2; m3 = n3;
  }
  if (lane < 16) {
    for (int jb = 0; jb < 64; ++jb) {
      int j = lane * 64 + jb;
      if (j < 1000) {
        double ss = sc0[bl * 1000 + j];
        sc0[bl * 1000 + j] = ((keepw >> jb) & 1) ? ss : -1.0;
      }
    }
  }
}

__global__ __launch_bounds__(1024) void final_k(const double* __restrict__ sc0,
                                                const double* __restrict__ boxes,
                                                float* __restrict__ out) {
  int b = blockIdx.x;
  __shared__ u64 s[8192];
  for (int i = threadIdx.x; i < 8192; i += 1024) {
    u64 v = 0;
    if (i < 5000) {
      u64 k = d2k(sc0[b * 5000 + i]);
      v = ((k >> 18) << 18) | (u64)(0x3FFFFu - (u32)i);
    }
    s[i] = v;
  }
  __syncthreads();
  bitonic_desc_n(s, 8192);
  for (int r = threadIdx.x; r < 1000; r += 1024) {
    u64 v = s[r];
    int idx = (int)(0x3FFFFu - (u32)(v & 0x3FFFFu));
    double score = sc0[b * 5000 + idx];
    const double* bp = boxes + (size_t)(b * 5000 + idx) * 4;
    float* op = out + ((size_t)b * 1000 + r) * 5;
    op[0] = (float)bp[0]; op[1] = (float)bp[1];
    op[2] = (float)bp[2]; op[3] = (float)bp[3];
    op[4] = (float)score;
  }
}

// ---------------- host ----------------
extern "C" void kernel_launch(void* const* d_in, const int* in_sizes, int n_in,
                              void* d_out, int out_size, void* d_ws, size_t ws_size,
                              hipStream_t stream) {
  const float* p[5];
  for (int i = 0; i < 5; ++i) p[i] = (const float*)d_in[i];
  const float* conv_w = (const float*)d_in[5];
  const float* conv_b = (const float*)d_in[6];
  const float* cls_w  = (const float*)d_in[7];
  const float* cls_b  = (const float*)d_in[8];
  const float* reg_w  = (const float*)d_in[9];
  const float* reg_b  = (const float*)d_in[10];
  float* out = (float*)d_out;

  char* ws = (char*)d_ws;
  size_t off = 0;
  auto alloc = [&](size_t bytes) -> void* {
    void* pt = ws + off;
    off = (off + bytes + 255) & ~(size_t)255;
    return pt;
  };
  const size_t XTB = (size_t)2 * PXPAD * 256 * 2 + 65536;     // 85.0 MB per array
  float*  wt       = (float*) alloc(2304ull * 256 * 4);       // 2.36 MB (rescore)
  short*  wbh      = (short*) alloc(73728ull * 8 * 2);        // 1.18 MB
  short*  xh       = (short*) alloc(XTB);                     // 85 MB
  short*  xl       = (short*) alloc(XTB);                     // 85 MB
  float*  scr32    = (float*) alloc(2ull * ATOT * 4);         // 1.94 MB
  double* scr64    = (double*)alloc(2ull * ATOT * 8);         // 3.89 MB
  double* reg64    = (double*)alloc(2ull * ATOT * 4 * 8);     // 15.55 MB
  u32*    hist     = (u32*)   alloc(40ull * 65536 * 4);       // 10.5 MB (4 replicas)
  int*    meta     = (int*)   alloc(10ull * 8 * 4);
  u32*    complist = (u32*)   alloc(10ull * 8192 * 4);
  u8*     flags    = (u8*)    alloc(2ull * PXTOT);
  u32*    worklist = (u32*)   alloc(65536ull * 4);
  int*    wlcount  = (int*)   alloc(256);
  int*    topidx   = (int*)   alloc(10ull * 1000 * 4);
  double* boxes    = (double*)alloc(2ull * 5000 * 4 * 8);
  double* sc0      = (double*)alloc(2ull * 5000 * 8);
  u64*    gmask    = (u64*)   alloc(10ull * 1000 * 16 * 8);

  prep_k<<<2716, 256, 0, stream>>>(conv_w, wt, wbh, xh, xl);
  xcvt_k<<<5064, 256, 0, stream>>>(p[0], p[1], p[2], p[3], p[4], xh, xl);
  conv_mfma_k<<<2876, 512, 0, stream>>>(xh, wbh, conv_b, cls_w, cls_b, scr32);

  int nblk = (2 * ATOT + 255) / 256;
  hipMemsetAsync(hist, 0, 40ull * 65536 * 4, stream);
  hist_hi_k<<<nblk, 256, 0, stream>>>(scr32, hist);
  scan_hi_k<<<10, 256, 0, stream>>>(hist, meta);
  hipMemsetAsync(hist, 0, 40ull * 65536 * 4, stream);
  hist_lo_k<<<nblk, 256, 0, stream>>>(scr32, meta, hist);
  scan_lo_k<<<10, 256, 0, stream>>>(hist, meta);

  hipMemsetAsync(flags, 0, 2ull * PXTOT, stream);
  hipMemsetAsync(wlcount, 0, 4, stream);
  compact_k<<<nblk, 256, 0, stream>>>(scr32, meta, complist, flags);
  pxcompact_k<<<(2 * PXTOT + 255) / 256, 256, 0, stream>>>(flags, worklist, wlcount);

  rescore_k<<<RSG, 256, 0, stream>>>(xh, xl, wt, conv_b, cls_w, cls_b, reg_w, reg_b,
                                     worklist, wlcount, scr64, reg64);

  sort_level_k<<<10, 1024, 0, stream>>>(complist, meta, scr64, topidx);
  decode_k<<<40, 256, 0, stream>>>(topidx, scr64, reg64, boxes, sc0);
  nms_mask_k<<<40, 256, 0, stream>>>(boxes, gmask);
  nms_scan_k<<<10, 64, 0, stream>>>(sc0, gmask);
  final_k<<<2, 1024, 0, stream>>>(sc0, boxes, out);
}

// Round 15
// 1840.975 us; speedup vs baseline: 1.2155x; 1.2155x over previous
//
#include <hip/hip_runtime.h>
#include <stdint.h>
#include <math.h>

typedef unsigned long long u64;
typedef unsigned int u32;
typedef unsigned char u8;
typedef short s16x8 __attribute__((ext_vector_type(8)));
typedef float f32x4 __attribute__((ext_vector_type(4)));

#define ATOT 242991    // total anchors per batch
#define PXTOT 80997    // total pixels per batch
#define PXPAD 82971    // padded (H+2)x(W+2) pixels per batch

__device__ __constant__ int    d_Hs[5]      = {200,100,50,25,13};
__device__ __constant__ int    d_Ws[5]      = {304,152,76,38,19};
__device__ __constant__ int    d_Wp[5]      = {306,154,78,40,21};
__device__ __constant__ int    d_stridec[5] = {4,8,16,32,64};
__device__ __constant__ double d_sized[5]   = {32.0,64.0,128.0,256.0,512.0};
__device__ __constant__ int    d_off[5]     = {0,182400,228000,239400,242250};
__device__ __constant__ int    d_pxoff[6]   = {0,60800,76000,79800,80750,80997};
__device__ __constant__ int    d_poff[5]    = {0,61812,77520,81576,82656};
__device__ __constant__ int    d_Ncand[5]   = {182400,45600,11400,2850,741};
// xcvt: 32-px chunks per level {1900,475,119,30,8} -> 2532/batch
__device__ __constant__ int    d_xcb[5]     = {0,1900,2375,2494,2524};
// conv: single-row 64-px tiles: {1000,300,100,25,13} = 1438/batch
__device__ __constant__ int    d_ctb[5]     = {0,1000,1300,1400,1425};
__device__ __constant__ int    d_tX[5]      = {5,3,2,1,1};
// border pixels per level: 2*(W+2)+2*H -> cumsum
__device__ __constant__ int    d_bcum[6]    = {0,1012,1520,1776,1906,1974};

__device__ __forceinline__ u32 f2k32(float f) {
  u32 u = __float_as_uint(f);
  return (u & 0x80000000u) ? ~u : (u | 0x80000000u);
}
__device__ __forceinline__ float k2f32(u32 k) {
  u32 u = (k & 0x80000000u) ? (k & 0x7FFFFFFFu) : ~k;
  return __uint_as_float(u);
}
__device__ __forceinline__ u64 d2k(double d) {
  u64 b = (u64)__double_as_longlong(d);
  return (b & 0x8000000000000000ull) ? ~b : (b | 0x8000000000000000ull);
}
__device__ __forceinline__ unsigned short f2bf(float v) {   // RNE (weights)
  u32 b = __float_as_uint(v);
  return (unsigned short)((b + 0x7FFFu + ((b >> 16) & 1u)) >> 16);
}

// ---------------- merged prep: wtrans (2304 blks) + wcvt (288) + border_zero (124) ----
__global__ void prep_k(const float* __restrict__ w, float* __restrict__ wt,
                       short* __restrict__ wbh, short* __restrict__ xh,
                       short* __restrict__ xl) {
  int blk = blockIdx.x;
  int t = threadIdx.x;
  if (blk < 2304) {
    // wtrans: w[oc][ic][3][3] -> wt[ic][tap][oc]  (fp32, r9-proven rescore operand)
    int gid = blk * 256 + t;
    int oc = gid & 255;
    int rest = gid >> 8;
    int ic = rest / 9, tap = rest % 9;
    wt[gid] = w[(oc * 256 + ic) * 9 + tap];
  } else if (blk < 2304 + 288) {
    int gid = (blk - 2304) * 256 + t;
    if (gid >= 73728) return;
    int lane = gid & 63;
    int rest = gid >> 6;
    int oct = rest & 15, rs = rest >> 4;
    int slice = rs & 7, tap = rs >> 3;
    int oc = oct * 16 + (lane & 15);
    int icb = slice * 32 + (lane >> 4) * 8;
    size_t ob = (size_t)gid * 8;
#pragma unroll
    for (int j = 0; j < 8; ++j)
      wbh[ob + j] = (short)f2bf(w[(oc * 256 + icb + j) * 9 + tap]);
  } else {
    int tid = (blk - 2592) * 256 + t;
    if (tid >= 2 * 1974 * 8) return;
    int oct = tid & 7;
    int rest = tid >> 3;
    int b = rest / 1974;
    int bi = rest % 1974;
    int lvl = 0;
#pragma unroll
    for (int l = 1; l < 5; ++l) if (bi >= d_bcum[l]) lvl = l;
    int li = bi - d_bcum[lvl];
    int W = d_Ws[lvl], H = d_Hs[lvl], Wp = d_Wp[lvl];
    int py, px;
    if (li < Wp)            { py = 0;     px = li; }
    else if (li < 2 * Wp)   { py = H + 1; px = li - Wp; }
    else { int rem = li - 2 * Wp; py = 1 + rem / 2; px = (rem & 1) ? (W + 1) : 0; }
    size_t base = ((size_t)(b * PXPAD + d_poff[lvl]) + (size_t)py * Wp + px) * 256
                + (size_t)oct * 32;
    s16x8 z = (s16x8){0,0,0,0,0,0,0,0};
#pragma unroll
    for (int j = 0; j < 4; ++j) {
      *(s16x8*)(xh + base + j * 8) = z;
      *(s16x8*)(xl + base + j * 8) = z;
    }
  }
}

// ---------------- x NCHW fp32 -> NHWC-padded BITWISE split (hi=top16, lo=bottom16) ----
__global__ __launch_bounds__(256) void xcvt_k(
    const float* __restrict__ x0, const float* __restrict__ x1,
    const float* __restrict__ x2, const float* __restrict__ x3,
    const float* __restrict__ x4, short* __restrict__ xh, short* __restrict__ xl)
{
  __shared__ float tile[32 * 257];
  const int bid = blockIdx.x;
  const int b = bid / 2532;
  int r = bid % 2532;
  int lvl = 0;
#pragma unroll
  for (int l2 = 1; l2 < 5; ++l2) if (r >= d_xcb[l2]) lvl = l2;
  const int chunk = r - d_xcb[lvl];
  const int H = d_Hs[lvl], W = d_Ws[lvl], HW = H * W, Wp = d_Wp[lvl];
  const int px0 = chunk * 32;
  const float* xs[5] = {x0, x1, x2, x3, x4};
  const float* xb = xs[lvl] + (size_t)b * 256 * HW;
  const int t = threadIdx.x;

  for (int icg = 0; icg < 32; ++icg) {
    int ic = icg * 8 + (t >> 5);
    int px = px0 + (t & 31);
    float v = (px < HW) ? xb[(size_t)ic * HW + px] : 0.f;
    tile[(t & 31) * 257 + ic] = v;
  }
  __syncthreads();
  int px = t >> 3, sub = t & 7;
  int gpx = px0 + px;
  if (gpx < HW) {
    int yy = gpx / W, xx = gpx % W;
    size_t pxbase = ((size_t)(b * PXPAD + d_poff[lvl]) +
                     (size_t)(yy + 1) * Wp + (xx + 1)) * 256;
#pragma unroll
    for (int q = 0; q < 4; ++q) {
      int ch0 = q * 64 + sub * 8;
      s16x8 hi, lo;
#pragma unroll
      for (int j = 0; j < 8; ++j) {
        u32 bits = __float_as_uint(tile[px * 257 + ch0 + j]);
        hi[j] = (short)(bits >> 16);       // truncated bf16 (screen operand)
        lo[j] = (short)(bits & 0xFFFFu);   // exact low bits (rescore reconstruct)
      }
      *(s16x8*)(xh + pxbase + ch0) = hi;
      *(s16x8*)(xl + pxbase + ch0) = lo;
    }
  }
}

// ---------------- 1-term bf16 MFMA conv3x3 + ReLU + in-register cls screen ----------
// r8/r13-proven optimum: 4 waves x 64 oc/wave, 1 row x 64 px tile.
__global__ __launch_bounds__(256) void conv_mfma_k(
    const short* __restrict__ xh, const short* __restrict__ wbh,
    const float* __restrict__ convb, const float* __restrict__ clsw,
    const float* __restrict__ clsb, float* __restrict__ scr32)
{
  __shared__ float zl[4][64][3];
  const int bid = blockIdx.x;
  const int b = bid / 1438;
  int r = bid % 1438;
  int lvl = 0;
#pragma unroll
  for (int l2 = 1; l2 < 5; ++l2) if (r >= d_ctb[l2]) lvl = l2;
  const int lid = r - d_ctb[lvl];
  const int tX = d_tX[lvl];
  const int y = lid / tX, x0 = (lid % tX) * 64;
  const int W = d_Ws[lvl], Wp = d_Wp[lvl];
  const size_t pbase = (size_t)(b * PXPAD + d_poff[lvl]);

  const int t = threadIdx.x;
  const int lane = t & 63;
  const int wid = t >> 6;
  const int aoff = (lane & 15) * 256 + (lane >> 4) * 8;

  f32x4 acc[4][4];
#pragma unroll
  for (int m = 0; m < 4; ++m)
#pragma unroll
    for (int o = 0; o < 4; ++o) acc[m][o] = (f32x4){0.f, 0.f, 0.f, 0.f};

#pragma unroll 1
  for (int tap = 0; tap < 9; ++tap) {
    const int ky = tap / 3, kx = tap % 3;
    const size_t re = (pbase + (size_t)(y + ky) * Wp + (x0 + kx)) * 256;
    const short* pa = xh + re;
    const short* pbh = wbh + (size_t)tap * 8 * 16 * 512;
#pragma unroll 1
    for (int slice = 0; slice < 8; ++slice) {
      s16x8 bh[4], a[4];
#pragma unroll
      for (int o = 0; o < 4; ++o) {
        size_t bo = ((size_t)(slice * 16 + wid * 4 + o) * 64 + lane) * 8;
        bh[o] = *(const s16x8*)(pbh + bo);
      }
#pragma unroll
      for (int m = 0; m < 4; ++m) {
        size_t ao = (size_t)aoff + slice * 32 + m * 4096;
        a[m] = *(const s16x8*)(pa + ao);
      }
#pragma unroll
      for (int m = 0; m < 4; ++m)
#pragma unroll
        for (int o = 0; o < 4; ++o)
          acc[m][o] = __builtin_amdgcn_mfma_f32_16x16x32_bf16(a[m], bh[o], acc[m][o], 0, 0, 0);
    }
  }

  float bb[4], cw0[4], cw1[4], cw2[4];
#pragma unroll
  for (int o = 0; o < 4; ++o) {
    int oc = wid * 64 + o * 16 + (lane & 15);
    bb[o]  = convb[oc];
    cw0[o] = clsw[0 * 256 + oc];
    cw1[o] = clsw[1 * 256 + oc];
    cw2[o] = clsw[2 * 256 + oc];
  }
#pragma unroll
  for (int m = 0; m < 4; ++m) {
#pragma unroll
    for (int q = 0; q < 4; ++q) {
      float h0 = fmaxf(acc[m][0][q] + bb[0], 0.f);
      float h1 = fmaxf(acc[m][1][q] + bb[1], 0.f);
      float h2 = fmaxf(acc[m][2][q] + bb[2], 0.f);
      float h3 = fmaxf(acc[m][3][q] + bb[3], 0.f);
      float z0 = fmaf(h0, cw0[0], fmaf(h1, cw0[1], fmaf(h2, cw0[2], h3 * cw0[3])));
      float z1 = fmaf(h0, cw1[0], fmaf(h1, cw1[1], fmaf(h2, cw1[2], h3 * cw1[3])));
      float z2 = fmaf(h0, cw2[0], fmaf(h1, cw2[1], fmaf(h2, cw2[2], h3 * cw2[3])));
      z0 += __shfl_xor(z0, 1); z0 += __shfl_xor(z0, 2); z0 += __shfl_xor(z0, 4); z0 += __shfl_xor(z0, 8);
      z1 += __shfl_xor(z1, 1); z1 += __shfl_xor(z1, 2); z1 += __shfl_xor(z1, 4); z1 += __shfl_xor(z1, 8);
      z2 += __shfl_xor(z2, 1); z2 += __shfl_xor(z2, 2); z2 += __shfl_xor(z2, 4); z2 += __shfl_xor(z2, 8);
      if ((lane & 15) == 0) {
        int slot = m * 16 + (lane >> 4) * 4 + q;
        zl[wid][slot][0] = z0; zl[wid][slot][1] = z1; zl[wid][slot][2] = z2;
      }
    }
  }
  __syncthreads();
  if (t < 192) {
    int slot = t / 3, head = t % 3;
    int col = x0 + slot;
    if (col < W) {
      float z = zl[0][slot][head] + zl[1][slot][head] + zl[2][slot][head] +
                zl[3][slot][head] + clsb[head];
      int pix = y * W + col;
      scr32[(size_t)b * ATOT + d_off[lvl] + (size_t)pix * 3 + head] =
          1.f / (1.f + expf(-z));
    }
  }
}

// ---------------- PHASE B: fp32 radix select with safety margin ----------------
__device__ __forceinline__ void locate(int gid, int& b, int& r, int& lvl) {
  b = gid / ATOT; r = gid % ATOT;
  lvl = (r < 182400) ? 0 : (r < 228000) ? 1 : (r < 239400) ? 2 : (r < 242250) ? 3 : 4;
}

__global__ void hist_hi_k(const float* __restrict__ scr, u32* __restrict__ hist) {
  int gid = blockIdx.x * 256 + threadIdx.x;
  if (gid >= 2 * ATOT) return;
  int b, r, lvl; locate(gid, b, r, lvl);
  u32 key = f2k32(scr[gid]);
  int rep = blockIdx.x & 3;
  atomicAdd(&hist[((((b * 5 + lvl) << 2) | rep) << 16) + (key >> 16)], 1u);
}

__global__ void scan_hi_k(const u32* __restrict__ hist, int* __restrict__ meta) {
  int bl = blockIdx.x, lvl = bl % 5;
  u32 k_sel = (u32)min(1000, d_Ncand[lvl]);
  const u32* h = hist + ((size_t)bl << 18);
  __shared__ u32 part[256];
  __shared__ u32 row[256];
  __shared__ int csel;
  __shared__ u32 cumsh;
  int t = threadIdx.x;
  u32 s = 0;
  for (int v = 0; v < 256; ++v) {
    int idx = t * 256 + v;
    s += h[idx] + h[65536 + idx] + h[131072 + idx] + h[196608 + idx];
  }
  part[t] = s;
  __syncthreads();
  if (t == 0) {
    u32 cum = 0; int c = 255;
    for (; c > 0; --c) { if (cum + part[c] >= k_sel) break; cum += part[c]; }
    csel = c; cumsh = cum;
  }
  __syncthreads();
  {
    int idx = csel * 256 + t;
    row[t] = h[idx] + h[65536 + idx] + h[131072 + idx] + h[196608 + idx];
  }
  __syncthreads();
  if (t == 0) {
    u32 cum = cumsh;
    int pivot = csel * 256;
    for (int v = 255; v >= 0; --v) {
      if (cum + row[v] >= k_sel) { pivot = csel * 256 + v; break; }
      cum += row[v];
    }
    meta[bl * 8 + 0] = pivot;
    meta[bl * 8 + 1] = (int)cum;
  }
}

__global__ void hist_lo_k(const float* __restrict__ scr, const int* __restrict__ meta,
                          u32* __restrict__ hist) {
  int gid = blockIdx.x * 256 + threadIdx.x;
  if (gid >= 2 * ATOT) return;
  int b, r, lvl; locate(gid, b, r, lvl);
  int bl = b * 5 + lvl;
  u32 key = f2k32(scr[gid]);
  if ((int)(key >> 16) == meta[bl * 8 + 0]) {
    int rep = blockIdx.x & 3;
    atomicAdd(&hist[(((bl << 2) | rep) << 16) + (key & 0xFFFFu)], 1u);
  }
}

__global__ void scan_lo_k(const u32* __restrict__ hist, int* __restrict__ meta) {
  int bl = blockIdx.x, lvl = bl % 5;
  u32 k_sel = (u32)min(1000, d_Ncand[lvl]);
  const u32* h = hist + ((size_t)bl << 18);
  __shared__ u32 part[256];
  __shared__ u32 row[256];
  __shared__ int csel;
  __shared__ u32 cumsh;
  int t = threadIdx.x;
  u32 s = 0;
  for (int v = 0; v < 256; ++v) {
    int idx = t * 256 + v;
    s += h[idx] + h[65536 + idx] + h[131072 + idx] + h[196608 + idx];
  }
  part[t] = s;
  __syncthreads();
  if (t == 0) {
    u32 cum = (u32)meta[bl * 8 + 1];
    int c = 255;
    for (; c > 0; --c) { if (cum + part[c] >= k_sel) break; cum += part[c]; }
    csel = c; cumsh = cum;
  }
  __syncthreads();
  {
    int idx = csel * 256 + t;
    row[t] = h[idx] + h[65536 + idx] + h[131072 + idx] + h[196608 + idx];
  }
  __syncthreads();
  if (t == 0) {
    u32 cum = cumsh;
    int pivot = csel * 256;
    for (int v = 255; v >= 0; --v) {
      if (cum + row[v] >= k_sel) { pivot = csel * 256 + v; break; }
      cum += row[v];
    }
    u32 P = (((u32)meta[bl * 8 + 0]) << 16) | (u32)pivot;   // exact fp32 kth key
    u32 T = f2k32(k2f32(P) - 5e-3f);                        // margin covers 1-term err
    if (d_Ncand[lvl] <= 1000) T = 0;                        // keep all
    meta[bl * 8 + 2] = (int)T;
    meta[bl * 8 + 4] = 0;   // compact counter
  }
}

__global__ void compact_k(const float* __restrict__ scr, int* __restrict__ meta,
                          u32* __restrict__ complist, u8* __restrict__ flags) {
  int gid = blockIdx.x * 256 + threadIdx.x;
  if (gid >= 2 * ATOT) return;
  int b, r, lvl; locate(gid, b, r, lvl);
  int bl = b * 5 + lvl;
  u32 key = f2k32(scr[gid]);
  if (key >= (u32)meta[bl * 8 + 2]) {
    int pos = atomicAdd(&meta[bl * 8 + 4], 1);
    if (pos < 8192) {
      u32 li = (u32)(r - d_off[lvl]);
      complist[bl * 8192 + pos] = li;
      flags[b * PXTOT + d_pxoff[lvl] + li / 3] = 1;
    }
  }
}

__global__ void pxcompact_k(u8* __restrict__ flags, u32* __restrict__ worklist,
                            int* __restrict__ wlcount) {
  int gid = blockIdx.x * 256 + threadIdx.x;
  if (gid >= 2 * PXTOT) return;
  if (flags[gid]) {
    flags[gid] = 0;
    int pos = atomicAdd(wlcount, 1);
    if (pos < 65536) worklist[pos] = (u32)gid;
  }
}

// ---------------- PHASE C: sparse fp64 rescore (round-9 proven structure) -----------
// x reconstructed BIT-EXACTLY as (xh<<16)|xl; fp32 wt (2.36 MB, L2-resident).
#define RSG 2048
__global__ __launch_bounds__(256) void rescore_k(
    const short* __restrict__ xh, const short* __restrict__ xl,
    const float* __restrict__ wt, const float* __restrict__ convb,
    const float* __restrict__ clsw, const float* __restrict__ clsb,
    const float* __restrict__ regw, const float* __restrict__ regb,
    const u32* __restrict__ worklist, const int* __restrict__ wlcount,
    double* __restrict__ scr64, double* __restrict__ reg64)
{
  __shared__ float xlb[4 * 2304];   // [slot][ic*9+tap]  36.9 KB
  __shared__ double hl[4 * 256];    // 8 KB -> total 45,056 B (r9-proven)
  const int t = threadIdx.x;
  int count = *wlcount; if (count > 65536) count = 65536;

  for (int base = blockIdx.x * 4; base < count; base += RSG * 4) {
    int sb[4], slvl[4], spix[4];
    size_t pb0[4];
    bool valid[4];
#pragma unroll
    for (int s = 0; s < 4; ++s) {
      int w = base + s;
      valid[s] = (w < count);
      sb[s] = 0; slvl[s] = 0; spix[s] = 0; pb0[s] = 0;
      if (valid[s]) {
        u32 g = worklist[w];
        int b = (int)(g / PXTOT), lp = (int)(g % PXTOT);
        int lvl = 0;
#pragma unroll
        for (int l = 1; l < 5; ++l) if (lp >= d_pxoff[l]) lvl = l;
        int pix = lp - d_pxoff[lvl];
        int W = d_Ws[lvl], Wp = d_Wp[lvl];
        int py = pix / W, px = pix % W;
        sb[s] = b; slvl[s] = lvl; spix[s] = pix;
        pb0[s] = ((size_t)(b * PXPAD + d_poff[lvl]) + (size_t)py * Wp + px) * 256;
      }
    }
    __syncthreads();
#pragma unroll
    for (int s = 0; s < 4; ++s) {
      if (valid[s]) {
        int Wp = d_Wp[slvl[s]];
        for (int i = t; i < 1152; i += 256) {
          int tap = i >> 7, pair = i & 127;
          int ky = tap / 3, kx = tap % 3;
          size_t po = pb0[s] + ((size_t)ky * Wp + kx) * 256 + (size_t)pair * 2;
          u32 vh = *(const u32*)(xh + po);
          u32 vl = *(const u32*)(xl + po);
          float xa  = __uint_as_float(((vh & 0xFFFFu) << 16) | (vl & 0xFFFFu));
          float xb2 = __uint_as_float((vh & 0xFFFF0000u) | (vl >> 16));
          xlb[s * 2304 + (pair * 2) * 9 + tap] = xa;
          xlb[s * 2304 + (pair * 2 + 1) * 9 + tap] = xb2;
        }
      }
    }
    __syncthreads();
    double h[4] = {0.0, 0.0, 0.0, 0.0};
    for (int ic = 0; ic < 256; ++ic) {
      double wd[9];
#pragma unroll
      for (int tap = 0; tap < 9; ++tap)
        wd[tap] = (double)wt[(ic * 9 + tap) * 256 + t];
#pragma unroll
      for (int s = 0; s < 4; ++s) {
        const float* xp = &xlb[s * 2304 + ic * 9];
#pragma unroll
        for (int tap = 0; tap < 9; ++tap)
          h[s] = fma((double)xp[tap], wd[tap], h[s]);
      }
    }
    double bias = (double)convb[t];
#pragma unroll
    for (int s = 0; s < 4; ++s) {
      h[s] = fmax(h[s] + bias, 0.0);
      hl[s * 256 + t] = h[s];
    }
    __syncthreads();
    {
      int s = t >> 6, lane = t & 63;
      if (valid[s]) {
        int lvl = slvl[s];
        size_t g3 = (size_t)sb[s] * ATOT + d_off[lvl] + (size_t)spix[s] * 3;
        for (int head = 0; head < 15; ++head) {
          const float* hw = (head < 3) ? (clsw + head * 256) : (regw + (head - 3) * 256);
          double part = 0.0;
#pragma unroll
          for (int q = 0; q < 4; ++q) {
            int oc = lane + q * 64;
            part = fma(hl[s * 256 + oc], (double)hw[oc], part);
          }
          part += __shfl_xor(part, 32);
          part += __shfl_xor(part, 16);
          part += __shfl_xor(part, 8);
          part += __shfl_xor(part, 4);
          part += __shfl_xor(part, 2);
          part += __shfl_xor(part, 1);
          if (lane == 0) {
            double z = part + (double)((head < 3) ? clsb[head] : regb[head - 3]);
            if (head < 3) scr64[g3 + head] = 1.0 / (1.0 + exp(-z));
            else { int hh = head - 3; reg64[(g3 + (hh >> 2)) * 4 + (hh & 3)] = z; }
          }
        }
      }
    }
    __syncthreads();
  }
}

// ---------------- PHASE D: keys built inline, sort, decode, NMS, final --------------
__device__ void bitonic_desc_n(u64* s, int SZ) {
  int t = threadIdx.x;
  for (int k = 2; k <= SZ; k <<= 1) {
    for (int j = k >> 1; j > 0; j >>= 1) {
      __syncthreads();
      for (int i = t; i < (SZ >> 1); i += 1024) {
        int l = (i << 1) - (i & (j - 1));
        int m = l + j;
        bool up = ((l & k) == 0);
        u64 a = s[l], bb = s[m];
        if ((a < bb) == up) { s[l] = bb; s[m] = a; }
      }
    }
  }
  __syncthreads();
}

__global__ __launch_bounds__(1024) void sort_level_k(const u32* __restrict__ complist,
                                                     const int* __restrict__ meta,
                                                     const double* __restrict__ scr64,
                                                     int* __restrict__ topidx) {
  int bl = blockIdx.x, lvl = bl % 5;
  int b = bl / 5;
  int k_sel = min(1000, d_Ncand[lvl]);
  __shared__ u64 s[8192];
  int M = meta[bl * 8 + 4]; if (M > 8192) M = 8192;
  int SZ = (M <= 2048) ? 2048 : 8192;
  for (int i = threadIdx.x; i < SZ; i += 1024) {
    u64 key = 0;
    if (i < M) {
      u32 li = complist[bl * 8192 + i];
      double sc = scr64[(size_t)b * ATOT + d_off[lvl] + li];
      key = ((d2k(sc) >> 18) << 18) | (u64)(0x3FFFFu - li);
    }
    s[i] = key;
  }
  __syncthreads();
  bitonic_desc_n(s, SZ);
  for (int r = threadIdx.x; r < 1000; r += 1024) {
    int v = -1;
    if (r < k_sel && r < M) v = (int)(0x3FFFFu - (u32)(s[r] & 0x3FFFFu));
    topidx[bl * 1000 + r] = v;
  }
}

__global__ void decode_k(const int* __restrict__ topidx, const double* __restrict__ scr64,
                         const double* __restrict__ reg64, double* __restrict__ boxes,
                         double* __restrict__ sc0) {
  int gid = blockIdx.x * 256 + threadIdx.x;
  if (gid >= 10000) return;
  int bl = gid / 1000, rank = gid % 1000;
  int b = bl / 5, lvl = bl % 5;
  int idx = topidx[bl * 1000 + rank];
  double X1 = 0.0, Y1 = 0.0, X2 = 0.0, Y2 = 0.0, sc = -1.0;
  if (idx >= 0) {
    size_t g = (size_t)b * ATOT + d_off[lvl] + idx;
    double s = scr64[g];
    double dx = reg64[g * 4 + 0], dy = reg64[g * 4 + 1];
    const double BCLIP = 4.135166556742356;
    double dw = fmin(reg64[g * 4 + 2], BCLIP);
    double dh = fmin(reg64[g * 4 + 3], BCLIP);
    int a = idx % 3, pix = idx / 3;
    int W = d_Ws[lvl];
    int py = pix / W, px = pix % W;
    double r = (a == 0) ? 2.0 : (a == 1) ? 1.0 : 0.5;
    double hr = sqrt(r);
    double size = d_sized[lvl];
    double wsz = size / hr, hsz = size * hr;
    double bx2 = rint(wsz * 0.5), by2 = rint(hsz * 0.5);
    double bx1 = rint(-(wsz * 0.5)), by1 = rint(-(hsz * 0.5));
    double sx = (double)(px * d_stridec[lvl]), sy = (double)(py * d_stridec[lvl]);
    double x1 = sx + bx1, yy1 = sy + by1;
    double x2 = sx + bx2, yy2 = sy + by2;
    double pw = x2 - x1, ph = yy2 - yy1;
    double pcx = x1 + 0.5 * pw, pcy = yy1 + 0.5 * ph;
    double cx = dx * pw + pcx, cy = dy * ph + pcy;
    double w = exp(dw) * pw, h = exp(dh) * ph;
    X1 = fmin(fmax(cx - 0.5 * w, 0.0), 1216.0);
    Y1 = fmin(fmax(cy - 0.5 * h, 0.0), 800.0);
    X2 = fmin(fmax(cx + 0.5 * w, 0.0), 1216.0);
    Y2 = fmin(fmax(cy + 0.5 * h, 0.0), 800.0);
    sc = ((X2 - X1) > 0.001 && (Y2 - Y1) > 0.001) ? s : -1.0;
  }
  double* bp = boxes + (size_t)(bl * 1000 + rank) * 4;
  bp[0] = X1; bp[1] = Y1; bp[2] = X2; bp[3] = Y2;
  sc0[bl * 1000 + rank] = sc;
}

__global__ __launch_bounds__(256) void nms_mask_k(const double* __restrict__ boxes,
                                                  u64* __restrict__ gmask) {
  int blk = blockIdx.x;
  int bl = blk >> 2, qt = blk & 3;
  __shared__ double X1[1000], Y1[1000], X2[1000], Y2[1000], AR[1000];
  int t = threadIdx.x;
  for (int i = t; i < 1000; i += 256) {
    const double* bp = boxes + (size_t)(bl * 1000 + i) * 4;
    double x1 = bp[0], y1 = bp[1], x2 = bp[2], y2 = bp[3];
    X1[i] = x1; Y1[i] = y1; X2[i] = x2; Y2[i] = y2;
    AR[i] = (x2 - x1) * (y2 - y1);
  }
  __syncthreads();
  if (t < 250) {
    int i = qt * 250 + t;
    double ax1 = X1[i], ay1 = Y1[i], ax2 = X2[i], ay2 = Y2[i], aa = AR[i];
    u64* gm = gmask + (size_t)bl * 16000 + (size_t)i * 16;
    for (int wj = 0; wj < 16; ++wj) {
      u64 bits = 0;
      int jb0 = wj * 64;
      for (int jb = 0; jb < 64; ++jb) {
        int j = jb0 + jb;
        if (j <= i || j >= 1000) continue;
        double lx = fmax(ax1, X1[j]), ly = fmax(ay1, Y1[j]);
        double rx = fmin(ax2, X2[j]), ry = fmin(ay2, Y2[j]);
        double ww = fmax(rx - lx, 0.0), hh = fmax(ry - ly, 0.0);
        double inter = ww * hh;
        double uni = (aa + AR[j]) - inter;
        double iou = inter / fmax(uni, 1e-9);
        if (iou > 0.7) bits |= (1ull << jb);
      }
      gm[wj] = bits;
    }
  }
}

__global__ void nms_scan_k(double* __restrict__ sc0, const u64* __restrict__ gmask) {
  int bl = blockIdx.x;
  int lane = threadIdx.x;
  const u64* gm = gmask + (size_t)bl * 16000;
  u64 keepw = 0;
  if (lane < 16) {
    for (int jb = 0; jb < 64; ++jb) {
      int j = lane * 64 + jb;
      if (j < 1000 && sc0[bl * 1000 + j] > -0.5) keepw |= (1ull << jb);
    }
  }
  u64 m0 = 0, m1 = 0, m2 = 0, m3 = 0;
  if (lane < 16) {
    m0 = gm[0 * 16 + lane]; m1 = gm[1 * 16 + lane];
    m2 = gm[2 * 16 + lane]; m3 = gm[3 * 16 + lane];
  }
  for (int i = 0; i < 1000; i += 4) {
    u64 n0 = 0, n1 = 0, n2 = 0, n3 = 0;
    if (lane < 16 && i + 4 < 1000) {
      n0 = gm[(i + 4) * 16 + lane]; n1 = gm[(i + 5) * 16 + lane];
      n2 = gm[(i + 6) * 16 + lane]; n3 = gm[(i + 7) * 16 + lane];
    }
    { u64 kw = __shfl(keepw, (i    ) >> 6); if ((kw >> ((i    ) & 63)) & 1) { if (lane < 16) keepw &= ~m0; } }
    { u64 kw = __shfl(keepw, (i + 1) >> 6); if ((kw >> ((i + 1) & 63)) & 1) { if (lane < 16) keepw &= ~m1; } }
    { u64 kw = __shfl(keepw, (i + 2) >> 6); if ((kw >> ((i + 2) & 63)) & 1) { if (lane < 16) keepw &= ~m2; } }
    { u64 kw = __shfl(keepw, (i + 3) >> 6); if ((kw >> ((i + 3) & 63)) & 1) { if (lane < 16) keepw &= ~m3; } }
    m0 = n0; m1 = n1; m2 = n2; m3 = n3;
  }
  if (lane < 16) {
    for (int jb = 0; jb < 64; ++jb) {
      int j = lane * 64 + jb;
      if (j < 1000) {
        double ss = sc0[bl * 1000 + j];
        sc0[bl * 1000 + j] = ((keepw >> jb) & 1) ? ss : -1.0;
      }
    }
  }
}

__global__ __launch_bounds__(1024) void final_k(const double* __restrict__ sc0,
                                                const double* __restrict__ boxes,
                                                float* __restrict__ out) {
  int b = blockIdx.x;
  __shared__ u64 s[8192];
  for (int i = threadIdx.x; i < 8192; i += 1024) {
    u64 v = 0;
    if (i < 5000) {
      u64 k = d2k(sc0[b * 5000 + i]);
      v = ((k >> 18) << 18) | (u64)(0x3FFFFu - (u32)i);
    }
    s[i] = v;
  }
  __syncthreads();
  bitonic_desc_n(s, 8192);
  for (int r = threadIdx.x; r < 1000; r += 1024) {
    u64 v = s[r];
    int idx = (int)(0x3FFFFu - (u32)(v & 0x3FFFFu));
    double score = sc0[b * 5000 + idx];
    const double* bp = boxes + (size_t)(b * 5000 + idx) * 4;
    float* op = out + ((size_t)b * 1000 + r) * 5;
    op[0] = (float)bp[0]; op[1] = (float)bp[1];
    op[2] = (float)bp[2]; op[3] = (float)bp[3];
    op[4] = (float)score;
  }
}

// ---------------- host ----------------
extern "C" void kernel_launch(void* const* d_in, const int* in_sizes, int n_in,
                              void* d_out, int out_size, void* d_ws, size_t ws_size,
                              hipStream_t stream) {
  const float* p[5];
  for (int i = 0; i < 5; ++i) p[i] = (const float*)d_in[i];
  const float* conv_w = (const float*)d_in[5];
  const float* conv_b = (const float*)d_in[6];
  const float* cls_w  = (const float*)d_in[7];
  const float* cls_b  = (const float*)d_in[8];
  const float* reg_w  = (const float*)d_in[9];
  const float* reg_b  = (const float*)d_in[10];
  float* out = (float*)d_out;

  char* ws = (char*)d_ws;
  size_t off = 0;
  auto alloc = [&](size_t bytes) -> void* {
    void* pt = ws + off;
    off = (off + bytes + 255) & ~(size_t)255;
    return pt;
  };
  const size_t XTB = (size_t)2 * PXPAD * 256 * 2 + 65536;     // 85.0 MB per array
  float*  wt       = (float*) alloc(2304ull * 256 * 4);       // 2.36 MB (rescore)
  short*  wbh      = (short*) alloc(73728ull * 8 * 2);        // 1.18 MB
  short*  xh       = (short*) alloc(XTB);                     // 85 MB
  short*  xl       = (short*) alloc(XTB);                     // 85 MB
  float*  scr32    = (float*) alloc(2ull * ATOT * 4);         // 1.94 MB
  double* scr64    = (double*)alloc(2ull * ATOT * 8);         // 3.89 MB
  double* reg64    = (double*)alloc(2ull * ATOT * 4 * 8);     // 15.55 MB
  u32*    hist     = (u32*)   alloc(40ull * 65536 * 4);       // 10.5 MB (4 replicas)
  int*    meta     = (int*)   alloc(10ull * 8 * 4);
  u32*    complist = (u32*)   alloc(10ull * 8192 * 4);
  u8*     flags    = (u8*)    alloc(2ull * PXTOT);
  u32*    worklist = (u32*)   alloc(65536ull * 4);
  int*    wlcount  = (int*)   alloc(256);
  int*    topidx   = (int*)   alloc(10ull * 1000 * 4);
  double* boxes    = (double*)alloc(2ull * 5000 * 4 * 8);
  double* sc0      = (double*)alloc(2ull * 5000 * 8);
  u64*    gmask    = (u64*)   alloc(10ull * 1000 * 16 * 8);

  prep_k<<<2716, 256, 0, stream>>>(conv_w, wt, wbh, xh, xl);
  xcvt_k<<<5064, 256, 0, stream>>>(p[0], p[1], p[2], p[3], p[4], xh, xl);
  conv_mfma_k<<<2876, 256, 0, stream>>>(xh, wbh, conv_b, cls_w, cls_b, scr32);

  int nblk = (2 * ATOT + 255) / 256;
  hipMemsetAsync(hist, 0, 40ull * 65536 * 4, stream);
  hist_hi_k<<<nblk, 256, 0, stream>>>(scr32, hist);
  scan_hi_k<<<10, 256, 0, stream>>>(hist, meta);
  hipMemsetAsync(hist, 0, 40ull * 65536 * 4, stream);
  hist_lo_k<<<nblk, 256, 0, stream>>>(scr32, meta, hist);
  scan_lo_k<<<10, 256, 0, stream>>>(hist, meta);

  hipMemsetAsync(flags, 0, 2ull * PXTOT, stream);
  hipMemsetAsync(wlcount, 0, 4, stream);
  compact_k<<<nblk, 256, 0, stream>>>(scr32, meta, complist, flags);
  pxcompact_k<<<(2 * PXTOT + 255) / 256, 256, 0, stream>>>(flags, worklist, wlcount);

  rescore_k<<<RSG, 256, 0, stream>>>(xh, xl, wt, conv_b, cls_w, cls_b, reg_w, reg_b,
                                     worklist, wlcount, scr64, reg64);

  sort_level_k<<<10, 1024, 0, stream>>>(complist, meta, scr64, topidx);
  decode_k<<<40, 256, 0, stream>>>(topidx, scr64, reg64, boxes, sc0);
  nms_mask_k<<<40, 256, 0, stream>>>(boxes, gmask);
  nms_scan_k<<<10, 64, 0, stream>>>(sc0, gmask);
  final_k<<<2, 1024, 0, stream>>>(sc0, boxes, out);
}